// Round 8
// baseline (1163.996 us; speedup 1.0000x reference)
//
#include <hip/hip_runtime.h>
#include <cstdint>
#include <cstddef>

#define Bn 128
#define Ln 1024
#define Fn 128
#define Hn 64
#define NGn 256           // 4*H
#define NCn 16
#define IN_DIM (Hn + Fn*Hn)   // 8256

typedef float    f32x4 __attribute__((ext_vector_type(4)));
typedef float    f32x2 __attribute__((ext_vector_type(2)));
typedef _Float16 f16x8 __attribute__((ext_vector_type(8)));
typedef _Float16 f16x2 __attribute__((ext_vector_type(2)));

struct SlabR { f16x8 w[8]; f32x2 wb; };   // 32 + 2 VGPRs
union U8 { f16x8 v; f16x2 p[4]; };

__device__ __forceinline__ float fsigm(float x) {
    return __fdividef(1.0f, 1.0f + __expf(-x));
}
__device__ __forceinline__ float ftanh(float x) {
    float e = __expf(2.0f * x);
    return 1.0f - __fdividef(2.0f, e + 1.0f);
}
__device__ __forceinline__ float sigm_slow(float x) { return 1.0f / (1.0f + expf(-x)); }

template<int P>
__device__ __forceinline__ float qperm(float v) {
    return __int_as_float(__builtin_amdgcn_mov_dpp(__float_as_int(v), P, 0xf, 0xf, true));
}
// quad all-reduce (sum)
#define QRED(A) do { A += qperm<0xB1>(A); A += qperm<0x4E>(A); } while (0)

#if __has_builtin(__builtin_amdgcn_fdot2)
#define DOT2(WP, HP, ACC) __builtin_amdgcn_fdot2((WP), (HP), (ACC), false)
#else
#define DOT2(WP, HP, ACC) fmaf((float)(WP)[0], (float)(HP)[0], \
                               fmaf((float)(WP)[1], (float)(HP)[1], (ACC)))
#endif

// thread tid: q = tid&3 (k-quarter AND bias-gate), u = (tid>>6)*16 + ((tid>>2)&15)
// Gw[((f*8 + c)*256 + tid)*8 + e] = (f16) W_gates[f][(c>>1)*64 + u][1 + 16q + 8*(c&1) + e]
// Gwb[f*256 + tid] = (W_gates[f][q*64+u][0], b_gates[f][q*64+u])
__global__ __launch_bounds__(256)
void prep_f16(const float* __restrict__ Wg, const float* __restrict__ bg,
              _Float16* __restrict__ Gw, f32x2* __restrict__ Gwb)
{
    const int f = blockIdx.x, tid = threadIdx.x;
    const int q = tid & 3;
    const int u = (tid >> 6) * 16 + ((tid >> 2) & 15);
    {
        const float* srcq = Wg + ((size_t)f * NGn + q * 64 + u) * 65;
        f32x2 wb; wb[0] = srcq[0]; wb[1] = bg[f * NGn + q * 64 + u];
        Gwb[f * NGn + tid] = wb;
    }
#pragma unroll
    for (int c = 0; c < 8; ++c) {
        const int r = c >> 1;
        const float* src = Wg + ((size_t)f * NGn + r * 64 + u) * 65;
        f16x8 v;
#pragma unroll
        for (int e = 0; e < 8; ++e) v[e] = (_Float16)src[1 + 16 * q + 8 * (c & 1) + e];
        *(f16x8*)(Gw + (((size_t)f * 8 + c) * NGn + tid) * 8) = v;
    }
}

// Issue one step's per-thread W chunk (9 pinned loads) into register slab SL.
#define ISSUE_R(SL, MN)                                                         \
    do {                                                                        \
        const uint32_t vo_ = ((uint32_t)(MN) << 15) + ((uint32_t)tid << 4);     \
        _Pragma("unroll")                                                       \
        for (int i_ = 0; i_ < 8; ++i_)                                          \
            asm volatile("global_load_dwordx4 %0, %1, %2"                       \
                         : "=v"(SL.w[i_])                                       \
                         : "v"(vo_ + (uint32_t)(i_ * 4096)), "s"(Gw));          \
        asm volatile("global_load_dwordx2 %0, %1, %2"                           \
                     : "=v"(SL.wb)                                              \
                     : "v"(((uint32_t)(MN) << 11) + ((uint32_t)tid << 3)),      \
                       "s"(Gwb));                                               \
    } while (0)

// 64-long dot (f16 pairs) for one sample: CUR slab vs hXa/hXb fragments.
#define DOT64(CUR, HXa, HXb, A0, A1, A2, A3)                                    \
    do {                                                                        \
        U8 wa_, wb2_;                                                           \
        wa_.v = CUR.w[0]; wb2_.v = CUR.w[1];                                    \
        _Pragma("unroll")                                                       \
        for (int e_ = 0; e_ < 4; ++e_) { A0 = DOT2(wa_.p[e_], HXa.p[e_], A0); A0 = DOT2(wb2_.p[e_], HXb.p[e_], A0); } \
        wa_.v = CUR.w[2]; wb2_.v = CUR.w[3];                                    \
        _Pragma("unroll")                                                       \
        for (int e_ = 0; e_ < 4; ++e_) { A1 = DOT2(wa_.p[e_], HXa.p[e_], A1); A1 = DOT2(wb2_.p[e_], HXb.p[e_], A1); } \
        wa_.v = CUR.w[4]; wb2_.v = CUR.w[5];                                    \
        _Pragma("unroll")                                                       \
        for (int e_ = 0; e_ < 4; ++e_) { A2 = DOT2(wa_.p[e_], HXa.p[e_], A2); A2 = DOT2(wb2_.p[e_], HXb.p[e_], A2); } \
        wa_.v = CUR.w[6]; wb2_.v = CUR.w[7];                                    \
        _Pragma("unroll")                                                       \
        for (int e_ = 0; e_ < 4; ++e_) { A3 = DOT2(wa_.p[e_], HXa.p[e_], A3); A3 = DOT2(wb2_.p[e_], HXb.p[e_], A3); } \
    } while (0)

// One step for BOTH samples. CA/CB consumed, FA/FB filled (step j+1).
#define STEP2(CA, FA, CB, FB)                                                   \
    {                                                                           \
        ISSUE_R(FA, m1A); ISSUE_R(FB, m1B);                                     \
        __builtin_amdgcn_sched_barrier(0);  /* pin: consume below issue */      \
        const int jpf_ = (j + 2 < lenM) ? j + 2 : lenM - 1;                     \
        const f32x2 pnA_ = pkA[jpf_]; const int mnA_ = (int)m8A[jpf_];          \
        const f32x2 pnB_ = pkB[jpf_]; const int mnB_ = (int)m8B[jpf_];          \
        asm volatile("s_waitcnt vmcnt(18)" ::: "memory"); /* CA,CB certified */ \
        __builtin_amdgcn_sched_barrier(0);                                      \
        float a0_=0.f,a1_=0.f,a2_=0.f,a3_=0.f,b0_=0.f,b1_=0.f,b2_=0.f,b3_=0.f;  \
        DOT64(CA, hAa, hAb, a0_, a1_, a2_, a3_);                                \
        DOT64(CB, hBa, hBb, b0_, b1_, b2_, b3_);                                \
        const float ownA_ = fmaf(CA.wb[0], xjA, CA.wb[1]);                      \
        a0_ = fmaf(a0_, djA, (q == 0) ? ownA_ : 0.0f);                          \
        a1_ = fmaf(a1_, djA, (q == 1) ? ownA_ : 0.0f);                          \
        a2_ = fmaf(a2_, djA, (q == 2) ? ownA_ : 0.0f);                          \
        a3_ = fmaf(a3_, djA, (q == 3) ? ownA_ : 0.0f);                          \
        const float ownB_ = fmaf(CB.wb[0], xjB, CB.wb[1]);                      \
        b0_ = fmaf(b0_, djB, (q == 0) ? ownB_ : 0.0f);                          \
        b1_ = fmaf(b1_, djB, (q == 1) ? ownB_ : 0.0f);                          \
        b2_ = fmaf(b2_, djB, (q == 2) ? ownB_ : 0.0f);                          \
        b3_ = fmaf(b3_, djB, (q == 3) ? ownB_ : 0.0f);                          \
        QRED(a0_); QRED(a1_); QRED(a2_); QRED(a3_);                             \
        QRED(b0_); QRED(b1_); QRED(b2_); QRED(b3_);                             \
        const float cnA_ = fmaf(fsigm(a1_), cuA, fsigm(a0_) * ftanh(a3_));      \
        const float cnB_ = fmaf(fsigm(b1_), cuB, fsigm(b0_) * ftanh(b3_));      \
        const float hvA_ = fsigm(a2_) * ftanh(cnA_);                            \
        const float hvB_ = fsigm(b2_) * ftanh(cnB_);                            \
        if (j < lenA) cuA = cnA_;                                               \
        if (j < lenB) cuB = cnB_;                                               \
        const float hpA_ = __int_as_float(__builtin_amdgcn_ds_swizzle(          \
                               __float_as_int(hvA_), 0x101F)); /* lane^4 */     \
        const float hpB_ = __int_as_float(__builtin_amdgcn_ds_swizzle(          \
                               __float_as_int(hvB_), 0x101F));                  \
        const int mwrA_ = mjA, mwrB_ = mjB;                                     \
        asm volatile("s_waitcnt lgkmcnt(0)" ::: "memory");                      \
        __builtin_amdgcn_sched_barrier(0);                                      \
        __builtin_amdgcn_s_barrier();   /* B1: all reads done */                \
        if ((l & 7) == 0) {                                                     \
            if (j < lenA) {                                                     \
                f16x2 pr_; pr_[0] = (_Float16)hvA_; pr_[1] = (_Float16)hpA_;    \
                *(f16x2*)(h16A + (mwrA_ << 6) + u) = pr_;                       \
            }                                                                   \
            if (j < lenB) {                                                     \
                f16x2 pr_; pr_[0] = (_Float16)hvB_; pr_[1] = (_Float16)hpB_;    \
                *(f16x2*)(h16B + (mwrB_ << 6) + u) = pr_;                       \
            }                                                                   \
        }                                                                       \
        if ((m1A == mjA) || (m1B == mjB)) {   /* block-uniform, P~2/128 */      \
            asm volatile("s_waitcnt lgkmcnt(0)" ::: "memory");                  \
            __builtin_amdgcn_s_barrier();     /* B2: same-row write->read */    \
        }                                                                       \
        asm volatile("" ::: "memory");        /* keep reads below cond-B2 */    \
        mjA = m1A; xjA = x1A; djA = d1A;                                        \
        m1A = mnA_; x1A = pnA_[0]; d1A = pnA_[1];                               \
        mjB = m1B; xjB = x1B; djB = d1B;                                        \
        m1B = mnB_; x1B = pnB_[0]; d1B = pnB_[1];                               \
        {   /* issue next step's h-row reads; latency hides under next top */   \
            const f16x8* hA2_ = (const f16x8*)(h16A + (mjA << 6) + (q << 4));   \
            hAa.v = hA2_[0]; hAb.v = hA2_[1];                                   \
            const f16x8* hB2_ = (const f16x8*)(h16B + (mjB << 6) + (q << 4));   \
            hBa.v = hB2_[0]; hBb.v = hB2_[1];                                   \
        }                                                                       \
    }

// 2 samples per block: A = 2*blockIdx, B = 2*blockIdx+1
__global__ __launch_bounds__(256, 1)
void lstm_pre2(const float* __restrict__ X, const int* __restrict__ lengths,
               const _Float16* __restrict__ Gw, const f32x2* __restrict__ Gwb,
               const float* __restrict__ wdec, const float* __restrict__ bdec,
               const float* __restrict__ Wo, const float* __restrict__ bo,
               float* __restrict__ out)
{
    __shared__ __align__(16) _Float16 h16A[Fn * Hn];   // 16 KB
    __shared__ __align__(16) _Float16 h16B[Fn * Hn];   // 16 KB
    __shared__ __align__(8)  f32x2 pkA[Ln];            // 8 KB {x, dec}
    __shared__ __align__(8)  f32x2 pkB[Ln];            // 8 KB
    __shared__ unsigned char m8A[Ln], m8B[Ln];         // 2 KB
    __shared__ float cA[Hn], cB[Hn];
    __shared__ float wd_s[Fn], bd_s[Fn];
    __shared__ float red_lds[4 * NCn];
    __shared__ float logit_lds[NCn];

    const int bb  = blockIdx.x;
    const int b0  = bb * 2, b1 = bb * 2 + 1;
    const int tid = threadIdx.x;
    const int l   = tid & 63;
    const int w   = tid >> 6;
    const int q   = l & 3;
    const int u   = w * 16 + (l >> 2);

    {
        f16x8 hz;
#pragma unroll
        for (int e = 0; e < 8; ++e) hz[e] = (_Float16)0.0f;
        for (int i = tid; i < (Fn * Hn / 8); i += 256) {
            ((f16x8*)h16A)[i] = hz;
            ((f16x8*)h16B)[i] = hz;
        }
    }
    if (tid < Fn) { wd_s[tid] = wdec[tid]; bd_s[tid] = bdec[tid]; }
    __syncthreads();

    {
        const float* mA = X + ((size_t)b0 * 4 + 1) * Ln;
        const float* xA = X + ((size_t)b0 * 4 + 2) * Ln;
        const float* dA = X + ((size_t)b0 * 4 + 3) * Ln;
        const float* mB = X + ((size_t)b1 * 4 + 1) * Ln;
        const float* xB = X + ((size_t)b1 * 4 + 2) * Ln;
        const float* dB = X + ((size_t)b1 * 4 + 3) * Ln;
        for (int jj = tid; jj < Ln; jj += 256) {
            int   m  = (int)mA[jj];
            float dec = __expf(-fmaxf(0.0f, fmaf(wd_s[m], dA[jj], bd_s[m])));
            f32x2 t; t[0] = xA[jj]; t[1] = dec;
            pkA[jj] = t; m8A[jj] = (unsigned char)m;
            m   = (int)mB[jj];
            dec = __expf(-fmaxf(0.0f, fmaf(wd_s[m], dB[jj], bd_s[m])));
            f32x2 t2; t2[0] = xB[jj]; t2[1] = dec;
            pkB[jj] = t2; m8B[jj] = (unsigned char)m;
        }
    }
    __syncthreads();

    int lenA = lengths[b0]; if (lenA > Ln) lenA = Ln;
    int lenB = lengths[b1]; if (lenB > Ln) lenB = Ln;
    const int lenM = (lenA > lenB) ? lenA : lenB;

    float cuA = 0.0f, cuB = 0.0f;

    if (lenM > 0) {
        int   mjA = (int)m8A[0], mjB = (int)m8B[0];
        f32x2 pA0 = pkA[0],      pB0 = pkB[0];
        float xjA = pA0[0], djA = pA0[1];
        float xjB = pB0[0], djB = pB0[1];
        const int i1 = (1 < lenM) ? 1 : 0;
        int   m1A = (int)m8A[i1], m1B = (int)m8B[i1];
        f32x2 pA1 = pkA[i1],      pB1 = pkB[i1];
        float x1A = pA1[0], d1A = pA1[1];
        float x1B = pB1[0], d1B = pB1[1];

        SlabR sA0, sA1, sB0, sB1;
        ISSUE_R(sA0, mjA); ISSUE_R(sB0, mjB);
        __builtin_amdgcn_sched_barrier(0);

        U8 hAa, hAb, hBa, hBb;
        {
            const f16x8* hA2 = (const f16x8*)(h16A + (mjA << 6) + (q << 4));
            hAa.v = hA2[0]; hAb.v = hA2[1];
            const f16x8* hB2 = (const f16x8*)(h16B + (mjB << 6) + (q << 4));
            hBa.v = hB2[0]; hBb.v = hB2[1];
        }

        int j = 0;
        for (;;) {
            STEP2(sA0, sA1, sB0, sB1); if (++j >= lenM) break;
            STEP2(sA1, sA0, sB1, sB0); if (++j >= lenM) break;
        }
        asm volatile("s_waitcnt vmcnt(0)" ::: "memory");
    }
    if (q == 0) { cA[u] = cuA; cB[u] = cuB; }
    __syncthreads();

    // ---- output head for both samples ----
    for (int s = 0; s < 2; ++s) {
        const _Float16* hh = s ? h16B : h16A;
        const float*    cc = s ? cB  : cA;
        float p[NCn];
#pragma unroll
        for (int c = 0; c < NCn; ++c) p[c] = 0.0f;
        for (int i = tid; i < IN_DIM; i += 256) {
            const float fv = (i < Hn) ? cc[i] : (float)hh[i - Hn];
#pragma unroll
            for (int c = 0; c < NCn; ++c)
                p[c] = fmaf(Wo[(size_t)c * IN_DIM + i], fv, p[c]);
        }
#pragma unroll
        for (int c = 0; c < NCn; ++c) {
            float v = p[c];
#pragma unroll
            for (int off = 32; off > 0; off >>= 1) v += __shfl_down(v, off, 64);
            if (l == 0) red_lds[w * NCn + c] = v;
        }
        __syncthreads();
        if (tid < NCn) {
            logit_lds[tid] = red_lds[tid] + red_lds[NCn + tid] +
                             red_lds[2 * NCn + tid] + red_lds[3 * NCn + tid] + bo[tid];
        }
        __syncthreads();
        if (tid == 0) {
            float mx = logit_lds[0];
            for (int c = 1; c < NCn; ++c) mx = fmaxf(mx, logit_lds[c]);
            float e[NCn], sm = 0.0f;
            for (int c = 0; c < NCn; ++c) { e[c] = expf(logit_lds[c] - mx); sm += e[c]; }
            const float inv = 1.0f / sm;
            for (int c = 0; c < NCn; ++c) out[(size_t)(b0 + s) * NCn + c] = e[c] * inv;
        }
        __syncthreads();
    }
}

// ---- fallback (no workspace): raw f32 weights each step ----
__global__ __launch_bounds__(256)
void lstm_fallback(const float* __restrict__ X, const int* __restrict__ lengths,
                   const float* __restrict__ Wg, const float* __restrict__ bg,
                   const float* __restrict__ wdec, const float* __restrict__ bdec,
                   const float* __restrict__ Wo, const float* __restrict__ bo,
                   float* __restrict__ out)
{
    __shared__ __align__(16) float h_lds[Fn * Hn];
    __shared__ float c_lds[Hn];
    __shared__ int   m_lds[Ln];
    __shared__ float x_lds[Ln];
    __shared__ float d_lds[Ln];
    __shared__ float wd_lds[Fn], bd_lds[Fn];
    __shared__ float red_lds[4 * NCn];
    __shared__ float logit_lds[NCn];

    const int b   = blockIdx.x;
    const int tid = threadIdx.x;
    const int l   = tid & 63;
    const int w   = tid >> 6;
    const int q   = l & 3;
    const int u   = w * 16 + (l >> 2);

    const float* mrow = X + ((size_t)b * 4 + 1) * Ln;
    const float* xrow = X + ((size_t)b * 4 + 2) * Ln;
    const float* drow = X + ((size_t)b * 4 + 3) * Ln;

    for (int i = tid; i < Fn * Hn; i += 256) h_lds[i] = 0.0f;
    if (tid < Hn) c_lds[tid] = 0.0f;
    if (tid < Fn) { wd_lds[tid] = wdec[tid]; bd_lds[tid] = bdec[tid]; }
    for (int i = tid; i < Ln; i += 256) {
        m_lds[i] = (int)mrow[i];
        x_lds[i] = xrow[i];
        d_lds[i] = drow[i];
    }
    __syncthreads();

    int len = lengths[b];
    if (len > Ln) len = Ln;
    const int g_raw = q * 64 + u;

    for (int j = 0; j < len; ++j) {
        const int   mj = m_lds[j];
        const float xj = x_lds[j];
        const float dj = d_lds[j];
        const float dec = expf(-fmaxf(0.0f, fmaf(wd_lds[mj], dj, bd_lds[mj])));
        const float4* hp = (const float4*)(h_lds + mj * Hn);
        const float* row = Wg + ((size_t)mj * NGn + g_raw) * 65;
        float acc = fmaf(row[0], xj, bg[mj * NGn + g_raw]);
        float a0 = 0.f, a1 = 0.f, a2 = 0.f, a3 = 0.f;
#pragma unroll
        for (int k4 = 0; k4 < 16; ++k4) {
            float4 hv = hp[k4];
            a0 = fmaf(row[1 + 4*k4 + 0], hv.x, a0);
            a1 = fmaf(row[1 + 4*k4 + 1], hv.y, a1);
            a2 = fmaf(row[1 + 4*k4 + 2], hv.z, a2);
            a3 = fmaf(row[1 + 4*k4 + 3], hv.w, a3);
        }
        acc = fmaf(dec, (a0 + a1) + (a2 + a3), acc);
        const int base = l & ~3;
        const float gi = __shfl(acc, base + 0, 64);
        const float gf = __shfl(acc, base + 1, 64);
        const float go = __shfl(acc, base + 2, 64);
        const float gc = __shfl(acc, base + 3, 64);
        __syncthreads();
        const float c_new = fmaf(sigm_slow(gf), c_lds[u], sigm_slow(gi) * tanhf(gc));
        if (q == 0) {
            c_lds[u] = c_new;
            h_lds[mj * Hn + u] = sigm_slow(go) * tanhf(c_new);
        }
        __syncthreads();
    }

    float p[NCn];
#pragma unroll
    for (int c = 0; c < NCn; ++c) p[c] = 0.0f;
    for (int i = tid; i < IN_DIM; i += 256) {
        const float fv = (i < Hn) ? c_lds[i] : h_lds[i - Hn];
#pragma unroll
        for (int c = 0; c < NCn; ++c)
            p[c] = fmaf(Wo[(size_t)c * IN_DIM + i], fv, p[c]);
    }
#pragma unroll
    for (int c = 0; c < NCn; ++c) {
        float v = p[c];
#pragma unroll
        for (int off = 32; off > 0; off >>= 1) v += __shfl_down(v, off, 64);
        if (l == 0) red_lds[w * NCn + c] = v;
    }
    __syncthreads();
    if (tid < NCn) {
        logit_lds[tid] = red_lds[tid] + red_lds[NCn + tid] +
                         red_lds[2 * NCn + tid] + red_lds[3 * NCn + tid] + bo[tid];
    }
    __syncthreads();
    if (tid == 0) {
        float mx = logit_lds[0];
        for (int c = 1; c < NCn; ++c) mx = fmaxf(mx, logit_lds[c]);
        float e[NCn], s = 0.0f;
        for (int c = 0; c < NCn; ++c) { e[c] = expf(logit_lds[c] - mx); s += e[c]; }
        const float inv = 1.0f / s;
        for (int c = 0; c < NCn; ++c) out[(size_t)b * NCn + c] = e[c] * inv;
    }
}

extern "C" void kernel_launch(void* const* d_in, const int* in_sizes, int n_in,
                              void* d_out, int out_size, void* d_ws, size_t ws_size,
                              hipStream_t stream)
{
    const float* X      = (const float*)d_in[0];
    const int*   len    = (const int*)  d_in[1];
    const float* Wg     = (const float*)d_in[2];
    const float* bg     = (const float*)d_in[3];
    const float* wdec   = (const float*)d_in[4];
    const float* bdec   = (const float*)d_in[5];
    const float* Wo     = (const float*)d_in[6];
    const float* bo     = (const float*)d_in[7];
    float*       out    = (float*)d_out;

    const size_t gw_bytes  = (size_t)Fn * 8 * NGn * 8 * sizeof(_Float16); // 4,194,304
    const size_t gwb_bytes = (size_t)Fn * NGn * sizeof(f32x2);            // 262,144
    const size_t need      = gw_bytes + gwb_bytes;

    if (ws_size >= need) {
        _Float16* Gw  = (_Float16*)d_ws;
        f32x2*    Gwb = (f32x2*)((char*)d_ws + gw_bytes);
        prep_f16<<<Fn, 256, 0, stream>>>(Wg, bg, Gw, Gwb);
        lstm_pre2<<<Bn / 2, 256, 0, stream>>>(X, len, Gw, Gwb,
                                              wdec, bdec, Wo, bo, out);
    } else {
        lstm_fallback<<<Bn, 256, 0, stream>>>(X, len, Wg, bg,
                                              wdec, bdec, Wo, bo, out);
    }
}

// Round 9
// 723.088 us; speedup vs baseline: 1.6098x; 1.6098x over previous
//
#include <hip/hip_runtime.h>
#include <cstdint>
#include <cstddef>

#define Bn 128
#define Ln 1024
#define Fn 128
#define Hn 64
#define NGn 256           // 4*H
#define NCn 16
#define IN_DIM (Hn + Fn*Hn)   // 8256
#define WMAX 8

typedef float    f32x2 __attribute__((ext_vector_type(2)));
typedef _Float16 f16x8 __attribute__((ext_vector_type(8)));
typedef _Float16 f16x2 __attribute__((ext_vector_type(2)));

typedef __attribute__((address_space(1))) const void* gas_t;
typedef __attribute__((address_space(3))) void*       las_t;

union U8 { f16x8 v; f16x2 p[4]; };

// ---- dynamic LDS carve (bytes) ----
#define OFF_H    0                        // 16384  h state f16 [128][64]
#define OFF_PK   16384                    // 8192   f32x2 {x, dec} per step
#define OFF_M8   24576                    // 1024   m per step (u8)
#define OFF_SZ   25600                    // 1024   window size from j (u8)
#define OFF_C    26624                    // 256    final c (f32)
#define OFF_WD   26880                    // 512
#define OFF_BD   27392                    // 512
#define OFF_RED  27904                    // 256
#define OFF_LOG  28160                    // 64
#define OFF_BUF  28672                    // 4 waves x 2 bufs x 9216
#define BUF_STRIDE_W 18432                // per-wave region
#define BUF_SEL      9216                 // per-buffer (8K W + 256 wx + 256 b + pad)
#define LDS_TOTAL (OFF_BUF + 4 * BUF_STRIDE_W)   // 102400

__device__ __forceinline__ float fsigm(float x) {
    return __fdividef(1.0f, 1.0f + __expf(-x));
}
__device__ __forceinline__ float ftanh(float x) {
    float e = __expf(2.0f * x);
    return 1.0f - __fdividef(2.0f, e + 1.0f);
}
__device__ __forceinline__ float sigm_slow(float x) { return 1.0f / (1.0f + expf(-x)); }

template<int P>
__device__ __forceinline__ float qperm(float v) {
    return __int_as_float(__builtin_amdgcn_mov_dpp(__float_as_int(v), P, 0xf, 0xf, true));
}
#define QRED(A) do { A += qperm<0xB1>(A); A += qperm<0x4E>(A); } while (0)

#if __has_builtin(__builtin_amdgcn_fdot2)
#define DOT2(WP, HP, ACC) __builtin_amdgcn_fdot2((WP), (HP), (ACC), false)
#else
#define DOT2(WP, HP, ACC) fmaf((float)(WP)[0], (float)(HP)[0], \
                               fmaf((float)(WP)[1], (float)(HP)[1], (ACC)))
#endif

// thread tid: q = tid&3 (k-quarter AND own-gate), u = (tid>>6)*16 + ((tid>>2)&15)
// Gw[((f*8 + c)*256 + tid)*8 + e] = (f16) W_gates[f][(c>>1)*64 + u][1 + 16q + 8*(c&1) + e]
// Gwx[f*256 + tid] = W_gates[f][q*64+u][0];  Gb[f*256+tid] = b_gates[f][q*64+u]
__global__ __launch_bounds__(256)
void prep_f16(const float* __restrict__ Wg, const float* __restrict__ bg,
              _Float16* __restrict__ Gw, float* __restrict__ Gwx, float* __restrict__ Gb)
{
    const int f = blockIdx.x, tid = threadIdx.x;
    const int q = tid & 3;
    const int u = (tid >> 6) * 16 + ((tid >> 2) & 15);
    {
        const float* srcq = Wg + ((size_t)f * NGn + q * 64 + u) * 65;
        Gwx[f * NGn + tid] = srcq[0];
        Gb [f * NGn + tid] = bg[f * NGn + q * 64 + u];
    }
#pragma unroll
    for (int c = 0; c < 8; ++c) {
        const int r = c >> 1;
        const float* src = Wg + ((size_t)f * NGn + r * 64 + u) * 65;
        f16x8 v;
#pragma unroll
        for (int e = 0; e < 8; ++e) v[e] = (_Float16)src[1 + 16 * q + 8 * (c & 1) + e];
        *(f16x8*)(Gw + (((size_t)f * 8 + c) * NGn + tid) * 8) = v;
    }
}

// Stage step slab MN into per-wave buffer SEL: 10 VMEM ops per wave
// (8 x 16B W + 2 x 4B wx/b). Per-wave private: no barrier ever needed.
#define STAGE(SEL, MN)                                                          \
    do {                                                                        \
        const _Float16* gs_ = Gw + (((size_t)(MN) * 8 * NGn) + tid) * 8;        \
        char* db_ = wbuf + (SEL) * BUF_SEL;                                     \
        _Pragma("unroll")                                                       \
        for (int c_ = 0; c_ < 8; ++c_)                                          \
            __builtin_amdgcn_global_load_lds(                                   \
                (gas_t)(const void*)(gs_ + c_ * (NGn * 8)),                     \
                (las_t)(void*)(db_ + c_ * 1024), 16, 0, 0);                     \
        __builtin_amdgcn_global_load_lds(                                       \
            (gas_t)(const void*)(Gwx + (MN) * NGn + tid),                       \
            (las_t)(void*)(db_ + 8192), 4, 0, 0);                               \
        __builtin_amdgcn_global_load_lds(                                       \
            (gas_t)(const void*)(Gb + (MN) * NGn + tid),                        \
            (las_t)(void*)(db_ + 8448), 4, 0, 0);                               \
    } while (0)

__global__ __launch_bounds__(256, 1)
void lstm_pre(const float* __restrict__ X, const int* __restrict__ lengths,
              const _Float16* __restrict__ Gw, const float* __restrict__ Gwx,
              const float* __restrict__ Gb,
              const float* __restrict__ wdec, const float* __restrict__ bdec,
              const float* __restrict__ Wo, const float* __restrict__ bo,
              float* __restrict__ out)
{
    extern __shared__ char smem[];
    _Float16* h16  = (_Float16*)(smem + OFF_H);
    f32x2*    pk_s = (f32x2*)   (smem + OFF_PK);
    unsigned char* m8_s = (unsigned char*)(smem + OFF_M8);
    unsigned char* sz_s = (unsigned char*)(smem + OFF_SZ);
    float* c_s  = (float*)(smem + OFF_C);
    float* wd_s = (float*)(smem + OFF_WD);
    float* bd_s = (float*)(smem + OFF_BD);
    float* red_lds   = (float*)(smem + OFF_RED);
    float* logit_lds = (float*)(smem + OFF_LOG);

    const int b   = blockIdx.x;
    const int tid = threadIdx.x;
    const int l   = tid & 63;
    const int w   = tid >> 6;
    const int q   = l & 3;              // k-quarter AND own-gate
    const int u   = w * 16 + (l >> 2);  // hidden unit owned by this quad
    char* wbuf = smem + OFF_BUF + w * BUF_STRIDE_W;

    const float* mrow = X + ((size_t)b * 4 + 1) * Ln;
    const float* xrow = X + ((size_t)b * 4 + 2) * Ln;
    const float* drow = X + ((size_t)b * 4 + 3) * Ln;

    {
        f16x8 hz;
#pragma unroll
        for (int e = 0; e < 8; ++e) hz[e] = (_Float16)0.0f;
        for (int i = tid; i < (Fn * Hn / 8); i += 256) ((f16x8*)h16)[i] = hz;
    }
    if (tid < Fn) { wd_s[tid] = wdec[tid]; bd_s[tid] = bdec[tid]; }
    __syncthreads();

    // per-step params {x, dec}, m
    for (int jj = tid; jj < Ln; jj += 256) {
        const int   m  = (int)mrow[jj];
        const float dec = __expf(-fmaxf(0.0f, fmaf(wd_s[m], drow[jj], bd_s[m])));
        f32x2 t; t[0] = xrow[jj]; t[1] = dec;
        pk_s[jj] = t; m8_s[jj] = (unsigned char)m;
    }
    __syncthreads();

    // szarr[j] = longest run of pairwise-distinct m starting at j (capped at 8)
    for (int j0 = tid; j0 < Ln; j0 += 256) {
        int mm[WMAX];
        mm[0] = (int)m8_s[j0];
        int s = 1;
#pragma unroll
        for (int i = 1; i < WMAX; ++i) {
            if (j0 + i < Ln) {
                const int mi = (int)m8_s[j0 + i];
                bool dup = false;
#pragma unroll
                for (int t2 = 0; t2 < i; ++t2) dup = dup || (mm[t2] == mi);
                mm[i] = mi;
                if (!dup && s == i) s = i + 1;
            }
        }
        sz_s[j0] = (unsigned char)s;
    }
    __syncthreads();

    int len = lengths[b];
    if (len > Ln) len = Ln;

    float cu = 0.0f;

    if (len > 0) {
        int   m_cur = (int)m8_s[0];
        int   m_nx  = (int)m8_s[(len > 1) ? 1 : 0];
        f32x2 p_cur = pk_s[0];
        f32x2 p_nx  = pk_s[(len > 1) ? 1 : 0];
        STAGE(0, m_cur);

        int jg = 0;
        while (jg < len) {
            int szc = (int)sz_s[jg];
            const int rem = len - jg;
            if (szc > rem) szc = rem;

            float sf[WMAX], ti[WMAX], sgo[WMAX], cs[WMAX];
            int   mwr[WMAX];

#pragma unroll
            for (int s = 0; s < WMAX; ++s) {
                if (s < szc) {
                    const int j = jg + s;
                    STAGE((j + 1) & 1, m_nx);
                    const int j2 = (j + 2 < len) ? (j + 2) : (len - 1);
                    const int   m_n2 = (int)m8_s[j2];
                    const f32x2 p_n2 = pk_s[j2];
                    U8 ha, hb;
                    {
                        const f16x8* hp = (const f16x8*)(h16 + (m_cur << 6) + (q << 4));
                        ha.v = hp[0]; hb.v = hp[1];
                    }
                    asm volatile("s_waitcnt vmcnt(10)" ::: "memory");  // slab j certified
                    __builtin_amdgcn_sched_barrier(0);
                    const char* db = wbuf + ((j & 1) * BUF_SEL);
                    U8 wf[8];
#pragma unroll
                    for (int c = 0; c < 8; ++c)
                        wf[c].v = *(const f16x8*)(db + c * 1024 + (l << 4));
                    const float wx = *(const float*)(db + 8192 + (l << 2));
                    const float bb = *(const float*)(db + 8448 + (l << 2));
                    asm volatile("s_waitcnt lgkmcnt(0)" ::: "memory");
                    __builtin_amdgcn_sched_barrier(0);
                    float a0 = 0.f, a1 = 0.f, a2 = 0.f, a3 = 0.f;
#pragma unroll
                    for (int e = 0; e < 4; ++e) {
                        a0 = DOT2(wf[0].p[e], ha.p[e], a0); a0 = DOT2(wf[1].p[e], hb.p[e], a0);
                        a1 = DOT2(wf[2].p[e], ha.p[e], a1); a1 = DOT2(wf[3].p[e], hb.p[e], a1);
                        a2 = DOT2(wf[4].p[e], ha.p[e], a2); a2 = DOT2(wf[5].p[e], hb.p[e], a2);
                        a3 = DOT2(wf[6].p[e], ha.p[e], a3); a3 = DOT2(wf[7].p[e], hb.p[e], a3);
                    }
                    const float own = fmaf(wx, p_cur[0], bb);
                    const float dj  = p_cur[1];
                    a0 = fmaf(a0, dj, (q == 0) ? own : 0.0f);
                    a1 = fmaf(a1, dj, (q == 1) ? own : 0.0f);
                    a2 = fmaf(a2, dj, (q == 2) ? own : 0.0f);
                    a3 = fmaf(a3, dj, (q == 3) ? own : 0.0f);
                    QRED(a0); QRED(a1); QRED(a2); QRED(a3);
                    sf[s]  = fsigm(a1);
                    ti[s]  = fsigm(a0) * ftanh(a3);
                    sgo[s] = fsigm(a2);
                    mwr[s] = m_cur;
                    m_cur = m_nx; m_nx = m_n2; p_cur = p_nx; p_nx = p_n2;
                }
            }

            asm volatile("s_waitcnt lgkmcnt(0)" ::: "memory");
            __builtin_amdgcn_s_barrier();   // B1: all h reads of this window done
#pragma unroll
            for (int s = 0; s < WMAX; ++s)
                if (s < szc) { cu = fmaf(sf[s], cu, ti[s]); cs[s] = cu; }
#pragma unroll
            for (int s = 0; s < WMAX; ++s) {
                if (s < szc) {
                    const float ho  = sgo[s] * ftanh(cs[s]);
                    const float hp2 = __int_as_float(__builtin_amdgcn_ds_swizzle(
                                          __float_as_int(ho), 0x101F));  // lane^4
                    if ((l & 7) == 0) {
                        f16x2 pr; pr[0] = (_Float16)ho; pr[1] = (_Float16)hp2;
                        *(f16x2*)(h16 + (mwr[s] << 6) + u) = pr;
                    }
                }
            }
            asm volatile("s_waitcnt lgkmcnt(0)" ::: "memory");
            __builtin_amdgcn_s_barrier();   // B2: h writes visible
            jg += szc;
        }
        asm volatile("s_waitcnt vmcnt(0)" ::: "memory");  // drain trailing stage
    }
    if (q == 0) c_s[u] = cu;
    __syncthreads();

    // ---- output head: logits = W_out @ [c; h.flatten()] + b_out, softmax ----
    float p[NCn];
#pragma unroll
    for (int c = 0; c < NCn; ++c) p[c] = 0.0f;
    for (int i = tid; i < IN_DIM; i += 256) {
        const float fv = (i < Hn) ? c_s[i] : (float)h16[i - Hn];
#pragma unroll
        for (int c = 0; c < NCn; ++c)
            p[c] = fmaf(Wo[(size_t)c * IN_DIM + i], fv, p[c]);
    }
#pragma unroll
    for (int c = 0; c < NCn; ++c) {
        float v = p[c];
#pragma unroll
        for (int off = 32; off > 0; off >>= 1) v += __shfl_down(v, off, 64);
        if (l == 0) red_lds[w * NCn + c] = v;
    }
    __syncthreads();
    if (tid < NCn) {
        logit_lds[tid] = red_lds[tid] + red_lds[NCn + tid] +
                         red_lds[2 * NCn + tid] + red_lds[3 * NCn + tid] + bo[tid];
    }
    __syncthreads();
    if (tid == 0) {
        float mx = logit_lds[0];
        for (int c = 1; c < NCn; ++c) mx = fmaxf(mx, logit_lds[c]);
        float e[NCn], sm = 0.0f;
        for (int c = 0; c < NCn; ++c) { e[c] = expf(logit_lds[c] - mx); sm += e[c]; }
        const float inv = 1.0f / sm;
        for (int c = 0; c < NCn; ++c) out[(size_t)b * NCn + c] = e[c] * inv;
    }
}

// ---- fallback (no workspace): raw f32 weights each step ----
__global__ __launch_bounds__(256)
void lstm_fallback(const float* __restrict__ X, const int* __restrict__ lengths,
                   const float* __restrict__ Wg, const float* __restrict__ bg,
                   const float* __restrict__ wdec, const float* __restrict__ bdec,
                   const float* __restrict__ Wo, const float* __restrict__ bo,
                   float* __restrict__ out)
{
    __shared__ __align__(16) float h_lds[Fn * Hn];
    __shared__ float c_lds[Hn];
    __shared__ int   m_lds[Ln];
    __shared__ float x_lds[Ln];
    __shared__ float d_lds[Ln];
    __shared__ float wd_lds[Fn], bd_lds[Fn];
    __shared__ float red_lds[4 * NCn];
    __shared__ float logit_lds[NCn];

    const int b   = blockIdx.x;
    const int tid = threadIdx.x;
    const int l   = tid & 63;
    const int w   = tid >> 6;
    const int q   = l & 3;
    const int u   = w * 16 + (l >> 2);

    const float* mrow = X + ((size_t)b * 4 + 1) * Ln;
    const float* xrow = X + ((size_t)b * 4 + 2) * Ln;
    const float* drow = X + ((size_t)b * 4 + 3) * Ln;

    for (int i = tid; i < Fn * Hn; i += 256) h_lds[i] = 0.0f;
    if (tid < Hn) c_lds[tid] = 0.0f;
    if (tid < Fn) { wd_lds[tid] = wdec[tid]; bd_lds[tid] = bdec[tid]; }
    for (int i = tid; i < Ln; i += 256) {
        m_lds[i] = (int)mrow[i];
        x_lds[i] = xrow[i];
        d_lds[i] = drow[i];
    }
    __syncthreads();

    int len = lengths[b];
    if (len > Ln) len = Ln;
    const int g_raw = q * 64 + u;

    for (int j = 0; j < len; ++j) {
        const int   mj = m_lds[j];
        const float xj = x_lds[j];
        const float dj = d_lds[j];
        const float dec = expf(-fmaxf(0.0f, fmaf(wd_lds[mj], dj, bd_lds[mj])));
        const float4* hp = (const float4*)(h_lds + mj * Hn);
        const float* row = Wg + ((size_t)mj * NGn + g_raw) * 65;
        float acc = fmaf(row[0], xj, bg[mj * NGn + g_raw]);
        float a0 = 0.f, a1 = 0.f, a2 = 0.f, a3 = 0.f;
#pragma unroll
        for (int k4 = 0; k4 < 16; ++k4) {
            float4 hv = hp[k4];
            a0 = fmaf(row[1 + 4*k4 + 0], hv.x, a0);
            a1 = fmaf(row[1 + 4*k4 + 1], hv.y, a1);
            a2 = fmaf(row[1 + 4*k4 + 2], hv.z, a2);
            a3 = fmaf(row[1 + 4*k4 + 3], hv.w, a3);
        }
        acc = fmaf(dec, (a0 + a1) + (a2 + a3), acc);
        const int base = l & ~3;
        const float gi = __shfl(acc, base + 0, 64);
        const float gf = __shfl(acc, base + 1, 64);
        const float go = __shfl(acc, base + 2, 64);
        const float gc = __shfl(acc, base + 3, 64);
        __syncthreads();
        const float c_new = fmaf(sigm_slow(gf), c_lds[u], sigm_slow(gi) * tanhf(gc));
        if (q == 0) {
            c_lds[u] = c_new;
            h_lds[mj * Hn + u] = sigm_slow(go) * tanhf(c_new);
        }
        __syncthreads();
    }

    float p[NCn];
#pragma unroll
    for (int c = 0; c < NCn; ++c) p[c] = 0.0f;
    for (int i = tid; i < IN_DIM; i += 256) {
        const float fv = (i < Hn) ? c_lds[i] : h_lds[i - Hn];
#pragma unroll
        for (int c = 0; c < NCn; ++c)
            p[c] = fmaf(Wo[(size_t)c * IN_DIM + i], fv, p[c]);
    }
#pragma unroll
    for (int c = 0; c < NCn; ++c) {
        float v = p[c];
#pragma unroll
        for (int off = 32; off > 0; off >>= 1) v += __shfl_down(v, off, 64);
        if (l == 0) red_lds[w * NCn + c] = v;
    }
    __syncthreads();
    if (tid < NCn) {
        logit_lds[tid] = red_lds[tid] + red_lds[NCn + tid] +
                         red_lds[2 * NCn + tid] + red_lds[3 * NCn + tid] + bo[tid];
    }
    __syncthreads();
    if (tid == 0) {
        float mx = logit_lds[0];
        for (int c = 1; c < NCn; ++c) mx = fmaxf(mx, logit_lds[c]);
        float e[NCn], s = 0.0f;
        for (int c = 0; c < NCn; ++c) { e[c] = expf(logit_lds[c] - mx); s += e[c]; }
        const float inv = 1.0f / s;
        for (int c = 0; c < NCn; ++c) out[(size_t)b * NCn + c] = e[c] * inv;
    }
}

extern "C" void kernel_launch(void* const* d_in, const int* in_sizes, int n_in,
                              void* d_out, int out_size, void* d_ws, size_t ws_size,
                              hipStream_t stream)
{
    const float* X      = (const float*)d_in[0];
    const int*   len    = (const int*)  d_in[1];
    const float* Wg     = (const float*)d_in[2];
    const float* bg     = (const float*)d_in[3];
    const float* wdec   = (const float*)d_in[4];
    const float* bdec   = (const float*)d_in[5];
    const float* Wo     = (const float*)d_in[6];
    const float* bo     = (const float*)d_in[7];
    float*       out    = (float*)d_out;

    const size_t gw_bytes = (size_t)Fn * 8 * NGn * 8 * sizeof(_Float16); // 4,194,304
    const size_t gx_bytes = (size_t)Fn * NGn * sizeof(float);            // 131,072
    const size_t need     = gw_bytes + 2 * gx_bytes;

    if (ws_size >= need) {
        _Float16* Gw  = (_Float16*)d_ws;
        float*    Gwx = (float*)((char*)d_ws + gw_bytes);
        float*    Gb  = Gwx + (size_t)Fn * NGn;
        prep_f16<<<Fn, 256, 0, stream>>>(Wg, bg, Gw, Gwx, Gb);
        (void)hipFuncSetAttribute((const void*)lstm_pre,
                                  hipFuncAttributeMaxDynamicSharedMemorySize,
                                  LDS_TOTAL);
        lstm_pre<<<Bn, 256, LDS_TOTAL, stream>>>(X, len, Gw, Gwx, Gb,
                                                 wdec, bdec, Wo, bo, out);
    } else {
        lstm_fallback<<<Bn, 256, 0, stream>>>(X, len, Wg, bg,
                                              wdec, bdec, Wo, bo, out);
    }
}

// Round 11
// 638.207 us; speedup vs baseline: 1.8239x; 1.1330x over previous
//
#include <hip/hip_runtime.h>
#include <cstdint>
#include <cstddef>

#define Bn 128
#define Ln 1024
#define Fn 128
#define Hn 64
#define NGn 256           // 4*H
#define NCn 16
#define IN_DIM (Hn + Fn*Hn)   // 8256

typedef float    f32x4 __attribute__((ext_vector_type(4)));
typedef float    f32x2 __attribute__((ext_vector_type(2)));
typedef _Float16 f16x8 __attribute__((ext_vector_type(8)));
typedef _Float16 f16x2 __attribute__((ext_vector_type(2)));

union U8 { f16x8 v; f16x2 p[4]; };
struct SlabR { f16x8 w[8]; f32x2 wb; };   // 32 + 2 VGPRs

__device__ __forceinline__ float fsigm(float x) {
    return __fdividef(1.0f, 1.0f + __expf(-x));
}
__device__ __forceinline__ float ftanh(float x) {
    float e = __expf(2.0f * x);
    return 1.0f - __fdividef(2.0f, e + 1.0f);
}
__device__ __forceinline__ float sigm_slow(float x) { return 1.0f / (1.0f + expf(-x)); }

template<int P>
__device__ __forceinline__ float qperm(float v) {
    return __int_as_float(__builtin_amdgcn_mov_dpp(__float_as_int(v), P, 0xf, 0xf, true));
}
#define QRED(A) do { A += qperm<0xB1>(A); A += qperm<0x4E>(A); } while (0)

#if __has_builtin(__builtin_amdgcn_fdot2)
#define DOT2(WP, HP, ACC) __builtin_amdgcn_fdot2((WP), (HP), (ACC), false)
#else
#define DOT2(WP, HP, ACC) fmaf((float)(WP)[0], (float)(HP)[0], \
                               fmaf((float)(WP)[1], (float)(HP)[1], (ACC)))
#endif

// thread tid: q = tid&3 (k-quarter AND own-gate), u = (tid>>6)*16 + ((tid>>2)&15)
// Gw[((f*8 + c)*256 + tid)*8 + e] = (f16) W_gates[f][(c>>1)*64 + u][1 + 16q + 8*(c&1) + e]
// Gwb[f*256 + tid] = (W_gates[f][q*64+u][0], b_gates[f][q*64+u])
__global__ __launch_bounds__(256)
void prep_f16(const float* __restrict__ Wg, const float* __restrict__ bg,
              _Float16* __restrict__ Gw, f32x2* __restrict__ Gwb)
{
    const int f = blockIdx.x, tid = threadIdx.x;
    const int q = tid & 3;
    const int u = (tid >> 6) * 16 + ((tid >> 2) & 15);
    {
        const float* srcq = Wg + ((size_t)f * NGn + q * 64 + u) * 65;
        f32x2 wb; wb[0] = srcq[0]; wb[1] = bg[f * NGn + q * 64 + u];
        Gwb[f * NGn + tid] = wb;
    }
#pragma unroll
    for (int c = 0; c < 8; ++c) {
        const int r = c >> 1;
        const float* src = Wg + ((size_t)f * NGn + r * 64 + u) * 65;
        f16x8 v;
#pragma unroll
        for (int e = 0; e < 8; ++e) v[e] = (_Float16)src[1 + 16 * q + 8 * (c & 1) + e];
        *(f16x8*)(Gw + (((size_t)f * 8 + c) * NGn + tid) * 8) = v;
    }
}

// One step consuming register slab CUR (loaded last step); loads step j+1's
// slab into NXT with PLAIN loads, kept alive by a no-op pin asm before B2.
#define STEPD(CUR, NXT)                                                         \
    {                                                                           \
        /* h fragments for this step (h-writes certified by prev B2) */         \
        U8 ha, hb;                                                              \
        {                                                                       \
            const f16x8* hp_ = (const f16x8*)(h16 + (mj << 6) + (q << 4));      \
            ha.v = hp_[0]; hb.v = hp_[1];                                       \
        }                                                                       \
        /* plain W(j+1) loads issued early; pinned alive at step tail */        \
        {                                                                       \
            const _Float16* wbp_ = Gw + ((size_t)m1 << 14) + (tid << 3);        \
            _Pragma("unroll")                                                   \
            for (int c_ = 0; c_ < 8; ++c_)                                      \
                NXT.w[c_] = *(const f16x8*)(wbp_ + (c_ << 11));                 \
            NXT.wb = Gwb[(m1 << 8) + tid];                                      \
        }                                                                       \
        const int jpf_ = (j + 2 < len) ? j + 2 : len - 1;                       \
        const f32x4 pn_ = pk_s[jpf_];                                           \
        float a0_ = 0.f, a1_ = 0.f, a2_ = 0.f, a3_ = 0.f;                       \
        {                                                                       \
            U8 w0_, w1_;                                                        \
            w0_.v = CUR.w[0]; w1_.v = CUR.w[1];                                 \
            _Pragma("unroll")                                                   \
            for (int e_ = 0; e_ < 4; ++e_) { a0_ = DOT2(w0_.p[e_], ha.p[e_], a0_); a0_ = DOT2(w1_.p[e_], hb.p[e_], a0_); } \
            w0_.v = CUR.w[2]; w1_.v = CUR.w[3];                                 \
            _Pragma("unroll")                                                   \
            for (int e_ = 0; e_ < 4; ++e_) { a1_ = DOT2(w0_.p[e_], ha.p[e_], a1_); a1_ = DOT2(w1_.p[e_], hb.p[e_], a1_); } \
            w0_.v = CUR.w[4]; w1_.v = CUR.w[5];                                 \
            _Pragma("unroll")                                                   \
            for (int e_ = 0; e_ < 4; ++e_) { a2_ = DOT2(w0_.p[e_], ha.p[e_], a2_); a2_ = DOT2(w1_.p[e_], hb.p[e_], a2_); } \
            w0_.v = CUR.w[6]; w1_.v = CUR.w[7];                                 \
            _Pragma("unroll")                                                   \
            for (int e_ = 0; e_ < 4; ++e_) { a3_ = DOT2(w0_.p[e_], ha.p[e_], a3_); a3_ = DOT2(w1_.p[e_], hb.p[e_], a3_); } \
        }                                                                       \
        const float own_ = fmaf(CUR.wb[0], xj, CUR.wb[1]);                      \
        a0_ = fmaf(a0_, dj, (q == 0) ? own_ : 0.0f);                            \
        a1_ = fmaf(a1_, dj, (q == 1) ? own_ : 0.0f);                            \
        a2_ = fmaf(a2_, dj, (q == 2) ? own_ : 0.0f);                            \
        a3_ = fmaf(a3_, dj, (q == 3) ? own_ : 0.0f);                            \
        QRED(a0_); QRED(a1_); QRED(a2_); QRED(a3_);                             \
        const float cn_ = fmaf(fsigm(a1_), cu, fsigm(a0_) * ftanh(a3_));        \
        cu = cn_;                                                               \
        const float ho_ = fsigm(a2_) * ftanh(cn_);                              \
        const float hs_ = __int_as_float(__builtin_amdgcn_ds_swizzle(           \
                              __float_as_int(ho_), 0x101F));  /* lane^4 */      \
        const int mwr_ = mj;                                                    \
        mj = m1; xj = x1; dj = d1;                                              \
        m1 = __float_as_int(pn_[2]); x1 = pn_[0]; d1 = pn_[1];                  \
        __builtin_amdgcn_s_barrier();   /* B1: all h reads done (consumed) */   \
        if ((l & 7) == 0) {                                                     \
            f16x2 pr_; pr_[0] = (_Float16)ho_; pr_[1] = (_Float16)hs_;          \
            *(f16x2*)(h16 + (mwr_ << 6) + u) = pr_;                             \
        }                                                                       \
        asm volatile("s_waitcnt lgkmcnt(0)" ::: "memory");                      \
        /* pin: forces W(j+1) values materialized (compiler inserts vmcnt) */   \
        asm volatile("" : "+v"(NXT.w[0]), "+v"(NXT.w[1]), "+v"(NXT.w[2]),       \
                          "+v"(NXT.w[3]), "+v"(NXT.w[4]), "+v"(NXT.w[5]),       \
                          "+v"(NXT.w[6]), "+v"(NXT.w[7]), "+v"(NXT.wb));        \
        __builtin_amdgcn_s_barrier();   /* B2: h writes visible */              \
    }

__global__ __launch_bounds__(256, 1)
void lstm_pre(const float* __restrict__ X, const int* __restrict__ lengths,
              const _Float16* __restrict__ Gw, const f32x2* __restrict__ Gwb,
              const float* __restrict__ wdec, const float* __restrict__ bdec,
              const float* __restrict__ Wo, const float* __restrict__ bo,
              float* __restrict__ out)
{
    __shared__ __align__(16) _Float16 h16[Fn * Hn];   // 16 KB f16 h state
    __shared__ __align__(16) f32x4 pk_s[Ln];          // 16 KB {x, dec, m_bits, 0}
    __shared__ float c_s[Hn];
    __shared__ float wd_s[Fn], bd_s[Fn];
    __shared__ float red_lds[4 * NCn];
    __shared__ float logit_lds[NCn];

    const int b   = blockIdx.x;
    const int tid = threadIdx.x;
    const int l   = tid & 63;
    const int w   = tid >> 6;
    const int q   = l & 3;              // k-quarter AND own-gate
    const int u   = w * 16 + (l >> 2);  // hidden unit owned by this quad

    const float* mrow = X + ((size_t)b * 4 + 1) * Ln;
    const float* xrow = X + ((size_t)b * 4 + 2) * Ln;
    const float* drow = X + ((size_t)b * 4 + 3) * Ln;

    {
        f16x8 hz;
#pragma unroll
        for (int e = 0; e < 8; ++e) hz[e] = (_Float16)0.0f;
        for (int i = tid; i < (Fn * Hn / 8); i += 256) ((f16x8*)h16)[i] = hz;
    }
    if (tid < Fn) { wd_s[tid] = wdec[tid]; bd_s[tid] = bdec[tid]; }
    __syncthreads();

    // precompute packed per-step params: {x, dec, m} (one broadcast b128/step)
    for (int jj = tid; jj < Ln; jj += 256) {
        const int   m  = (int)mrow[jj];
        const float dec = __expf(-fmaxf(0.0f, fmaf(wd_s[m], drow[jj], bd_s[m])));
        f32x4 t; t[0] = xrow[jj]; t[1] = dec; t[2] = __int_as_float(m); t[3] = 0.0f;
        pk_s[jj] = t;
    }
    __syncthreads();

    int len = lengths[b];
    if (len > Ln) len = Ln;

    float cu = 0.0f;   // c[u], replicated across the quad

    if (len > 0) {
        f32x4 p0 = pk_s[0];
        f32x4 p1 = pk_s[(1 < len) ? 1 : 0];
        int   mj = __float_as_int(p0[2]);
        float xj = p0[0], dj = p0[1];
        int   m1 = __float_as_int(p1[2]);
        float x1 = p1[0], d1 = p1[1];

        SlabR sA, sB;
        {   // prologue: load W(0) (plain; first consumption forces the wait)
            const _Float16* wbp = Gw + ((size_t)mj << 14) + (tid << 3);
#pragma unroll
            for (int c = 0; c < 8; ++c)
                sA.w[c] = *(const f16x8*)(wbp + (c << 11));
            sA.wb = Gwb[(mj << 8) + tid];
        }

        int j = 0;
        for (;;) {
            STEPD(sA, sB); if (++j >= len) break;
            STEPD(sB, sA); if (++j >= len) break;
        }
    }
    if (q == 0) c_s[u] = cu;
    __syncthreads();

    // ---- output head: logits = W_out @ [c; h.flatten()] + b_out, softmax ----
    float p[NCn];
#pragma unroll
    for (int c = 0; c < NCn; ++c) p[c] = 0.0f;
    for (int i = tid; i < IN_DIM; i += 256) {
        const float fv = (i < Hn) ? c_s[i] : (float)h16[i - Hn];
#pragma unroll
        for (int c = 0; c < NCn; ++c)
            p[c] = fmaf(Wo[(size_t)c * IN_DIM + i], fv, p[c]);
    }
#pragma unroll
    for (int c = 0; c < NCn; ++c) {
        float v = p[c];
#pragma unroll
        for (int off = 32; off > 0; off >>= 1) v += __shfl_down(v, off, 64);
        if (l == 0) red_lds[w * NCn + c] = v;
    }
    __syncthreads();
    if (tid < NCn) {
        logit_lds[tid] = red_lds[tid] + red_lds[NCn + tid] +
                         red_lds[2 * NCn + tid] + red_lds[3 * NCn + tid] + bo[tid];
    }
    __syncthreads();
    if (tid == 0) {
        float mx = logit_lds[0];
        for (int c = 1; c < NCn; ++c) mx = fmaxf(mx, logit_lds[c]);
        float e[NCn], sm = 0.0f;
        for (int c = 0; c < NCn; ++c) { e[c] = expf(logit_lds[c] - mx); sm += e[c]; }
        const float inv = 1.0f / sm;
        for (int c = 0; c < NCn; ++c) out[(size_t)b * NCn + c] = e[c] * inv;
    }
}

// ---- fallback (no workspace): raw f32 weights each step ----
__global__ __launch_bounds__(256)
void lstm_fallback(const float* __restrict__ X, const int* __restrict__ lengths,
                   const float* __restrict__ Wg, const float* __restrict__ bg,
                   const float* __restrict__ wdec, const float* __restrict__ bdec,
                   const float* __restrict__ Wo, const float* __restrict__ bo,
                   float* __restrict__ out)
{
    __shared__ __align__(16) float h_lds[Fn * Hn];
    __shared__ float c_lds[Hn];
    __shared__ int   m_lds[Ln];
    __shared__ float x_lds[Ln];
    __shared__ float d_lds[Ln];
    __shared__ float wd_lds[Fn], bd_lds[Fn];
    __shared__ float red_lds[4 * NCn];
    __shared__ float logit_lds[NCn];

    const int b   = blockIdx.x;
    const int tid = threadIdx.x;
    const int l   = tid & 63;
    const int w   = tid >> 6;
    const int q   = l & 3;
    const int u   = w * 16 + (l >> 2);

    const float* mrow = X + ((size_t)b * 4 + 1) * Ln;
    const float* xrow = X + ((size_t)b * 4 + 2) * Ln;
    const float* drow = X + ((size_t)b * 4 + 3) * Ln;

    for (int i = tid; i < Fn * Hn; i += 256) h_lds[i] = 0.0f;
    if (tid < Hn) c_lds[tid] = 0.0f;
    if (tid < Fn) { wd_lds[tid] = wdec[tid]; bd_lds[tid] = bdec[tid]; }
    for (int i = tid; i < Ln; i += 256) {
        m_lds[i] = (int)mrow[i];
        x_lds[i] = xrow[i];
        d_lds[i] = drow[i];
    }
    __syncthreads();

    int len = lengths[b];
    if (len > Ln) len = Ln;
    const int g_raw = q * 64 + u;

    for (int j = 0; j < len; ++j) {
        const int   mj = m_lds[j];
        const float xj = x_lds[j];
        const float dj = d_lds[j];
        const float dec = expf(-fmaxf(0.0f, fmaf(wd_lds[mj], dj, bd_lds[mj])));
        const float4* hp = (const float4*)(h_lds + mj * Hn);
        const float* row = Wg + ((size_t)mj * NGn + g_raw) * 65;
        float acc = fmaf(row[0], xj, bg[mj * NGn + g_raw]);
        float a0 = 0.f, a1 = 0.f, a2 = 0.f, a3 = 0.f;
#pragma unroll
        for (int k4 = 0; k4 < 16; ++k4) {
            float4 hv = hp[k4];
            a0 = fmaf(row[1 + 4*k4 + 0], hv.x, a0);
            a1 = fmaf(row[1 + 4*k4 + 1], hv.y, a1);
            a2 = fmaf(row[1 + 4*k4 + 2], hv.z, a2);
            a3 = fmaf(row[1 + 4*k4 + 3], hv.w, a3);
        }
        acc = fmaf(dec, (a0 + a1) + (a2 + a3), acc);
        const int base = l & ~3;
        const float gi = __shfl(acc, base + 0, 64);
        const float gf = __shfl(acc, base + 1, 64);
        const float go = __shfl(acc, base + 2, 64);
        const float gc = __shfl(acc, base + 3, 64);
        __syncthreads();
        const float c_new = fmaf(sigm_slow(gf), c_lds[u], sigm_slow(gi) * tanhf(gc));
        if (q == 0) {
            c_lds[u] = c_new;
            h_lds[mj * Hn + u] = sigm_slow(go) * tanhf(c_new);
        }
        __syncthreads();
    }

    float p[NCn];
#pragma unroll
    for (int c = 0; c < NCn; ++c) p[c] = 0.0f;
    for (int i = tid; i < IN_DIM; i += 256) {
        const float fv = (i < Hn) ? c_lds[i] : h_lds[i - Hn];
#pragma unroll
        for (int c = 0; c < NCn; ++c)
            p[c] = fmaf(Wo[(size_t)c * IN_DIM + i], fv, p[c]);
    }
#pragma unroll
    for (int c = 0; c < NCn; ++c) {
        float v = p[c];
#pragma unroll
        for (int off = 32; off > 0; off >>= 1) v += __shfl_down(v, off, 64);
        if (l == 0) red_lds[w * NCn + c] = v;
    }
    __syncthreads();
    if (tid < NCn) {
        logit_lds[tid] = red_lds[tid] + red_lds[NCn + tid] +
                         red_lds[2 * NCn + tid] + red_lds[3 * NCn + tid] + bo[tid];
    }
    __syncthreads();
    if (tid == 0) {
        float mx = logit_lds[0];
        for (int c = 1; c < NCn; ++c) mx = fmaxf(mx, logit_lds[c]);
        float e[NCn], s = 0.0f;
        for (int c = 0; c < NCn; ++c) { e[c] = expf(logit_lds[c] - mx); s += e[c]; }
        const float inv = 1.0f / s;
        for (int c = 0; c < NCn; ++c) out[(size_t)b * NCn + c] = e[c] * inv;
    }
}

extern "C" void kernel_launch(void* const* d_in, const int* in_sizes, int n_in,
                              void* d_out, int out_size, void* d_ws, size_t ws_size,
                              hipStream_t stream)
{
    const float* X      = (const float*)d_in[0];
    const int*   len    = (const int*)  d_in[1];
    const float* Wg     = (const float*)d_in[2];
    const float* bg     = (const float*)d_in[3];
    const float* wdec   = (const float*)d_in[4];
    const float* bdec   = (const float*)d_in[5];
    const float* Wo     = (const float*)d_in[6];
    const float* bo     = (const float*)d_in[7];
    float*       out    = (float*)d_out;

    const size_t gw_bytes  = (size_t)Fn * 8 * NGn * 8 * sizeof(_Float16); // 4,194,304
    const size_t gwb_bytes = (size_t)Fn * NGn * sizeof(f32x2);            // 262,144
    const size_t need      = gw_bytes + gwb_bytes;

    if (ws_size >= need) {
        _Float16* Gw  = (_Float16*)d_ws;
        f32x2*    Gwb = (f32x2*)((char*)d_ws + gw_bytes);
        prep_f16<<<Fn, 256, 0, stream>>>(Wg, bg, Gw, Gwb);
        lstm_pre<<<Bn, 256, 0, stream>>>(X, len, Gw, Gwb,
                                         wdec, bdec, Wo, bo, out);
    } else {
        lstm_fallback<<<Bn, 256, 0, stream>>>(X, len, Wg, bg,
                                              wdec, bdec, Wo, bo, out);
    }
}